// Round 1
// baseline (584.629 us; speedup 1.0000x reference)
//
#include <hip/hip_runtime.h>
#include <stdint.h>

typedef unsigned short u16t;
typedef __attribute__((ext_vector_type(8))) short frag8;   // 8 x bf16 (4 VGPRs)
typedef __attribute__((ext_vector_type(4))) float facc4;   // MFMA accumulator

#define S_LEN 2048
#define E_DIM 2048
#define M_TOT 8192   // B*S

__device__ __forceinline__ u16t f2bf(float f) {
    union { float f; uint32_t u; } c; c.f = f;
    return (u16t)((c.u + 0x7fffu + ((c.u >> 16) & 1u)) >> 16);  // RNE
}
__device__ __forceinline__ float bfu2f(uint32_t u) {
    union { uint32_t u; float f; } c; c.u = u << 16;
    return c.f;
}

// ---------------- fp32 -> bf16 conversion (vectorized) ----------------
__global__ __launch_bounds__(256) void cvt_kernel(const float* __restrict__ src,
                                                  u16t* __restrict__ dst, int n4) {
    int i = blockIdx.x * 256 + threadIdx.x;
    if (i >= n4) return;
    float4 v = ((const float4*)src)[i];
    ushort4 o;
    o.x = f2bf(v.x); o.y = f2bf(v.y); o.z = f2bf(v.z); o.w = f2bf(v.w);
    ((ushort4*)dst)[i] = o;
}

// ---------------- async global->LDS, 16B per lane ----------------
__device__ __forceinline__ void gldl16(const u16t* g, u16t* l) {
    __builtin_amdgcn_global_load_lds(
        (__attribute__((address_space(1))) void*)(g),
        (__attribute__((address_space(3))) void*)(l), 16, 0, 0);
}

// ---------------- GEMM core: C[128x128] = A[128xK] * B[128xK]^T ----------------
// A: row-major MxK (K=2048), Bw: row-major NxK. 256 threads = 4 waves,
// each wave does 64x64 via 4x4 grid of 16x16x32 bf16 MFMA.
__device__ __forceinline__ void gemm_core(const u16t* __restrict__ A,
                                          const u16t* __restrict__ Bw,
                                          u16t* As, u16t* Bs,
                                          facc4 acc[4][4]) {
    const int t    = threadIdx.x;
    const int lane = t & 63;
    const int wid  = t >> 6;
    const int m16  = lane & 15;
    const int quad = lane >> 4;
    const int wm   = (wid & 1) * 64;
    const int wn   = (wid >> 1) * 64;
    const size_t bm0 = (size_t)blockIdx.y * 128;
    const size_t bn0 = (size_t)blockIdx.x * 128;

#pragma unroll
    for (int i = 0; i < 4; ++i)
#pragma unroll
        for (int j = 0; j < 4; ++j) acc[i][j] = facc4{0.f, 0.f, 0.f, 0.f};

    const u16t* Ab = A + bm0 * E_DIM;
    const u16t* Bb = Bw + bn0 * E_DIM;

    // staging coords: LDS tile is row-major [128][32] bf16, unpadded
    // (global_load_lds scatters lane*16B from a wave-uniform base)
    const int e0 = wid * 512;          // elements; wave-uniform
    const int e1 = 2048 + wid * 512;
    const int le0 = e0 + lane * 8, le1 = e1 + lane * 8;
    const int r0 = le0 >> 5, c0 = le0 & 31;
    const int r1 = le1 >> 5, c1 = le1 & 31;

    for (int k0 = 0; k0 < E_DIM; k0 += 32) {
        __syncthreads();   // previous iter's LDS readers done
        gldl16(Ab + (size_t)r0 * E_DIM + k0 + c0, As + e0);
        gldl16(Ab + (size_t)r1 * E_DIM + k0 + c1, As + e1);
        gldl16(Bb + (size_t)r0 * E_DIM + k0 + c0, Bs + e0);
        gldl16(Bb + (size_t)r1 * E_DIM + k0 + c1, Bs + e1);
        __syncthreads();   // compiler drains vmcnt before s_barrier

        frag8 av[4], bv[4];
#pragma unroll
        for (int i = 0; i < 4; ++i)
            av[i] = *(const frag8*)(As + (wm + i * 16 + m16) * 32 + quad * 8);
#pragma unroll
        for (int j = 0; j < 4; ++j)
            bv[j] = *(const frag8*)(Bs + (wn + j * 16 + m16) * 32 + quad * 8);
#pragma unroll
        for (int i = 0; i < 4; ++i)
#pragma unroll
            for (int j = 0; j < 4; ++j)
                acc[i][j] = __builtin_amdgcn_mfma_f32_16x16x32_bf16(
                    av[i], bv[j], acc[i][j], 0, 0, 0);
    }
}

// ---------------- fused QKV projection (+bias, +RoPE for q,k) ----------------
struct QkvArgs {
    const u16t* w[3];
    const float* bias[3];
    u16t* out[3];
};

__global__ __launch_bounds__(256, 2)
void qkv_gemm(const u16t* __restrict__ xb, QkvArgs args,
              const float* __restrict__ fcos, const float* __restrict__ fsin) {
    __shared__ u16t As[128 * 32];
    __shared__ u16t Bs[128 * 32];
    facc4 acc[4][4];
    const int z = blockIdx.z;
    gemm_core(xb, args.w[z], As, Bs, acc);

    const int t    = threadIdx.x;
    const int lane = t & 63;
    const int m16  = lane & 15;
    const int quad = lane >> 4;
    const int wid  = t >> 6;
    const int wm   = (wid & 1) * 64;
    const int wn   = (wid >> 1) * 64;
    const int bm0  = blockIdx.y * 128;
    const int bn0  = blockIdx.x * 128;
    const bool rope = (z < 2);
    u16t* out = args.out[z];
    const float* bias = args.bias[z];

#pragma unroll
    for (int i = 0; i < 4; ++i) {
#pragma unroll
        for (int j = 0; j < 4; ++j) {
            const int n = bn0 + wn + j * 16 + m16;
            const float bn_ = bias[n];
#pragma unroll
            for (int r = 0; r < 4; ++r) {
                const int m = bm0 + wm + i * 16 + quad * 4 + r;
                float v = acc[i][j][r] + bn_;
                // RoPE: pair partner (n^1) lives in lane^1 (same quad, same reg)
                const float part = __shfl_xor(v, 1, 64);
                if (rope) {
                    const int s = m & (S_LEN - 1);
                    const int p = (n & 127) >> 1;
                    const float cs = fcos[s * 64 + p];
                    const float sn = fsin[s * 64 + p];
                    v = (n & 1) ? (part * sn + v * cs) : (v * cs - part * sn);
                }
                out[(size_t)m * E_DIM + n] = f2bf(v);
            }
        }
    }
}

// ---------------- output projection GEMM (fp32 out + bias) ----------------
__global__ __launch_bounds__(256, 2)
void out_gemm(const u16t* __restrict__ sh, const u16t* __restrict__ wob,
              const float* __restrict__ bo, float* __restrict__ out) {
    __shared__ u16t As[128 * 32];
    __shared__ u16t Bs[128 * 32];
    facc4 acc[4][4];
    gemm_core(sh, wob, As, Bs, acc);

    const int t    = threadIdx.x;
    const int lane = t & 63;
    const int m16  = lane & 15;
    const int quad = lane >> 4;
    const int wid  = t >> 6;
    const int wm   = (wid & 1) * 64;
    const int wn   = (wid >> 1) * 64;
    const int bm0  = blockIdx.y * 128;
    const int bn0  = blockIdx.x * 128;

#pragma unroll
    for (int i = 0; i < 4; ++i) {
#pragma unroll
        for (int j = 0; j < 4; ++j) {
            const int n = bn0 + wn + j * 16 + m16;
            const float bn_ = bo[n];
#pragma unroll
            for (int r = 0; r < 4; ++r) {
                const int m = bm0 + wm + i * 16 + quad * 4 + r;
                out[(size_t)m * E_DIM + n] = acc[i][j][r] + bn_;
            }
        }
    }
}

// ---------------- per-token head attention (16x16 over D=128) ----------------
// One block per token. Scores S[h][g] = q_h . k_g / sqrt(128); softmax over g;
// O[h][d] = sum_g P[h][g] V[g][d]; scatter to shuffled layout:
//   sh[b][h*128 + s/16][(s%16)*128 + d]
__global__ __launch_bounds__(256)
void attn_kernel(const u16t* __restrict__ qb, const u16t* __restrict__ kb,
                 const u16t* __restrict__ vb, u16t* __restrict__ sh) {
    __shared__ float Q[16][132];   // pad 132: row stride 4g mod 32 -> 2-way (free)
    __shared__ float Kt[16][132];
    __shared__ float V[16][132];
    __shared__ float P[16][17];

    const int tk = blockIdx.x;
    const int b  = tk >> 11;
    const int s  = tk & (S_LEN - 1);
    const int t  = threadIdx.x;
    const size_t row = (size_t)tk * E_DIM;

    const int rr = t >> 4;          // h
    const int cc = (t & 15) * 8;    // d block

    {
        uint4 pq = *(const uint4*)(qb + row + t * 8);
        uint4 pk = *(const uint4*)(kb + row + t * 8);
        uint4 pv = *(const uint4*)(vb + row + t * 8);
        float* qd = &Q[rr][cc];  float* kd = &Kt[rr][cc];  float* vd = &V[rr][cc];
        qd[0] = bfu2f(pq.x & 0xffff); qd[1] = bfu2f(pq.x >> 16);
        qd[2] = bfu2f(pq.y & 0xffff); qd[3] = bfu2f(pq.y >> 16);
        qd[4] = bfu2f(pq.z & 0xffff); qd[5] = bfu2f(pq.z >> 16);
        qd[6] = bfu2f(pq.w & 0xffff); qd[7] = bfu2f(pq.w >> 16);
        kd[0] = bfu2f(pk.x & 0xffff); kd[1] = bfu2f(pk.x >> 16);
        kd[2] = bfu2f(pk.y & 0xffff); kd[3] = bfu2f(pk.y >> 16);
        kd[4] = bfu2f(pk.z & 0xffff); kd[5] = bfu2f(pk.z >> 16);
        kd[6] = bfu2f(pk.w & 0xffff); kd[7] = bfu2f(pk.w >> 16);
        vd[0] = bfu2f(pv.x & 0xffff); vd[1] = bfu2f(pv.x >> 16);
        vd[2] = bfu2f(pv.y & 0xffff); vd[3] = bfu2f(pv.y >> 16);
        vd[4] = bfu2f(pv.z & 0xffff); vd[5] = bfu2f(pv.z >> 16);
        vd[6] = bfu2f(pv.w & 0xffff); vd[7] = bfu2f(pv.w >> 16);
    }
    __syncthreads();

    // scores: thread t handles (h=rr, g)
    const int g = t & 15;
    float sc = 0.f;
#pragma unroll 16
    for (int d = 0; d < 128; ++d) sc = fmaf(Q[rr][d], Kt[g][d], sc);
    sc *= 0.08838834764831845f;   // 1/sqrt(128)

    float mx = sc;
#pragma unroll
    for (int msk = 1; msk < 16; msk <<= 1) mx = fmaxf(mx, __shfl_xor(mx, msk, 64));
    float ex = __expf(sc - mx);
    float sm = ex;
#pragma unroll
    for (int msk = 1; msk < 16; msk <<= 1) sm += __shfl_xor(sm, msk, 64);
    P[rr][g] = ex / sm;
    __syncthreads();

    // O[h][cc..cc+7]
    float o[8];
#pragma unroll
    for (int i = 0; i < 8; ++i) o[i] = 0.f;
#pragma unroll
    for (int gg = 0; gg < 16; ++gg) {
        const float p = P[rr][gg];
#pragma unroll
        for (int i = 0; i < 8; ++i) o[i] = fmaf(p, V[gg][cc + i], o[i]);
    }
    union { u16t us[8]; uint4 v; } pko;
#pragma unroll
    for (int i = 0; i < 8; ++i) pko.us[i] = f2bf(o[i]);
    const size_t dst = ((size_t)b << 22)
                     + (size_t)(rr * 128 + (s >> 4)) * E_DIM
                     + (size_t)((s & 15) * 128 + cc);
    *(uint4*)(sh + dst) = pko.v;
}

// ---------------- launch ----------------
extern "C" void kernel_launch(void* const* d_in, const int* in_sizes, int n_in,
                              void* d_out, int out_size, void* d_ws, size_t ws_size,
                              hipStream_t stream) {
    const float* x    = (const float*)d_in[0];
    const float* fcos = (const float*)d_in[1];
    const float* fsin = (const float*)d_in[2];
    const float* wq   = (const float*)d_in[3];
    const float* bq   = (const float*)d_in[4];
    const float* wk   = (const float*)d_in[5];
    const float* bk   = (const float*)d_in[6];
    const float* wv   = (const float*)d_in[7];
    const float* bv   = (const float*)d_in[8];
    const float* wo   = (const float*)d_in[9];
    const float* bo   = (const float*)d_in[10];
    float* out = (float*)d_out;

    char* ws = (char*)d_ws;
    u16t* xb  = (u16t*)(ws);                      // 32 MB, reused as shuffled buf
    u16t* qb  = (u16t*)(ws + 33554432ull);
    u16t* kb  = (u16t*)(ws + 67108864ull);
    u16t* vb  = (u16t*)(ws + 100663296ull);
    u16t* wqb = (u16t*)(ws + 134217728ull);
    u16t* wkb = (u16t*)(ws + 142606336ull);
    u16t* wvb = (u16t*)(ws + 150994944ull);
    u16t* wob = (u16t*)(ws + 159383552ull);       // total 160 MB

    cvt_kernel<<<16384, 256, 0, stream>>>(x, xb, 4194304);
    cvt_kernel<<<4096, 256, 0, stream>>>(wq, wqb, 1048576);
    cvt_kernel<<<4096, 256, 0, stream>>>(wk, wkb, 1048576);
    cvt_kernel<<<4096, 256, 0, stream>>>(wv, wvb, 1048576);
    cvt_kernel<<<4096, 256, 0, stream>>>(wo, wob, 1048576);

    QkvArgs qa;
    qa.w[0] = wqb; qa.w[1] = wkb; qa.w[2] = wvb;
    qa.bias[0] = bq; qa.bias[1] = bk; qa.bias[2] = bv;
    qa.out[0] = qb; qa.out[1] = kb; qa.out[2] = vb;
    qkv_gemm<<<dim3(16, 64, 3), 256, 0, stream>>>(xb, qa, fcos, fsin);

    attn_kernel<<<8192, 256, 0, stream>>>(qb, kb, vb, xb);

    out_gemm<<<dim3(16, 64), 256, 0, stream>>>(xb, wob, bo, out);
}

// Round 2
// 520.007 us; speedup vs baseline: 1.1243x; 1.1243x over previous
//
#include <hip/hip_runtime.h>
#include <stdint.h>

typedef unsigned short u16t;
typedef __attribute__((ext_vector_type(8))) short frag8;   // 8 x bf16 (4 VGPRs)
typedef __attribute__((ext_vector_type(4))) float facc4;   // MFMA accumulator

#define S_LEN 2048
#define E_DIM 2048

__device__ __forceinline__ u16t f2bf(float f) {
    union { float f; uint32_t u; } c; c.f = f;
    return (u16t)((c.u + 0x7fffu + ((c.u >> 16) & 1u)) >> 16);  // RNE
}

// ---------------- fp32 -> bf16 conversion (vectorized) ----------------
__global__ __launch_bounds__(256) void cvt_kernel(const float* __restrict__ src,
                                                  u16t* __restrict__ dst, int n4) {
    int i = blockIdx.x * 256 + threadIdx.x;
    if (i >= n4) return;
    float4 v = ((const float4*)src)[i];
    ushort4 o;
    o.x = f2bf(v.x); o.y = f2bf(v.y); o.z = f2bf(v.z); o.w = f2bf(v.w);
    ((ushort4*)dst)[i] = o;
}

// ---------------- async global->LDS, 16B per lane ----------------
__device__ __forceinline__ void gldl16(const u16t* g, u16t* l) {
    __builtin_amdgcn_global_load_lds(
        (__attribute__((address_space(1))) void*)(g),
        (__attribute__((address_space(3))) void*)(l), 16, 0, 0);
}

// ---------------- GEMM core: C[128x128] = A[128xK] * B[128xK]^T ----------------
// BK=64 staged as two independent 128x32 half-tiles (keeps the conflict-free
// 64B row stride AND the wave-uniform-base constraint of global_load_lds).
// 32 MFMA per barrier pair per wave (vs 16 at BK=32).
__device__ __forceinline__ void gemm_core(const u16t* __restrict__ A,
                                          const u16t* __restrict__ Bw,
                                          u16t* As0, u16t* As1,
                                          u16t* Bs0, u16t* Bs1,
                                          facc4 acc[4][4]) {
    const int t    = threadIdx.x;
    const int lane = t & 63;
    const int wid  = t >> 6;
    const int m16  = lane & 15;
    const int quad = lane >> 4;
    const int wm   = (wid & 1) * 64;
    const int wn   = (wid >> 1) * 64;
    const size_t bm0 = (size_t)blockIdx.y * 128;
    const size_t bn0 = (size_t)blockIdx.x * 128;

#pragma unroll
    for (int i = 0; i < 4; ++i)
#pragma unroll
        for (int j = 0; j < 4; ++j) acc[i][j] = facc4{0.f, 0.f, 0.f, 0.f};

    const u16t* Ab = A + bm0 * E_DIM;
    const u16t* Bb = Bw + bn0 * E_DIM;

    // staging coords for one 128x32 half-tile (row-major, unpadded)
    const int e0 = wid * 512;
    const int e1 = 2048 + wid * 512;
    const int le0 = e0 + lane * 8, le1 = e1 + lane * 8;
    const int r0 = le0 >> 5, c0 = le0 & 31;
    const int r1 = le1 >> 5, c1 = le1 & 31;
    const size_t ga0 = (size_t)r0 * E_DIM + c0;
    const size_t ga1 = (size_t)r1 * E_DIM + c1;

    for (int k0 = 0; k0 < E_DIM; k0 += 64) {
        __syncthreads();   // previous iter's LDS readers done
        gldl16(Ab + ga0 + k0,      As0 + e0);
        gldl16(Ab + ga1 + k0,      As0 + e1);
        gldl16(Ab + ga0 + k0 + 32, As1 + e0);
        gldl16(Ab + ga1 + k0 + 32, As1 + e1);
        gldl16(Bb + ga0 + k0,      Bs0 + e0);
        gldl16(Bb + ga1 + k0,      Bs0 + e1);
        gldl16(Bb + ga0 + k0 + 32, Bs1 + e0);
        gldl16(Bb + ga1 + k0 + 32, Bs1 + e1);
        __syncthreads();   // drain vmcnt + barrier

#pragma unroll
        for (int h = 0; h < 2; ++h) {
            const u16t* Ah = h ? As1 : As0;
            const u16t* Bh = h ? Bs1 : Bs0;
            frag8 av[4], bv[4];
#pragma unroll
            for (int i = 0; i < 4; ++i)
                av[i] = *(const frag8*)(Ah + (wm + i * 16 + m16) * 32 + quad * 8);
#pragma unroll
            for (int j = 0; j < 4; ++j)
                bv[j] = *(const frag8*)(Bh + (wn + j * 16 + m16) * 32 + quad * 8);
#pragma unroll
            for (int i = 0; i < 4; ++i)
#pragma unroll
                for (int j = 0; j < 4; ++j)
                    acc[i][j] = __builtin_amdgcn_mfma_f32_16x16x32_bf16(
                        av[i], bv[j], acc[i][j], 0, 0, 0);
        }
    }
}

// ---------------- fused QKV projection (+bias, +RoPE for q,k) ----------------
struct QkvArgs {
    const u16t* w[3];
    const float* bias[3];
    u16t* out[3];
};

__global__ __launch_bounds__(256, 2)
void qkv_gemm(const u16t* __restrict__ xb, QkvArgs args,
              const float* __restrict__ fcos, const float* __restrict__ fsin) {
    __shared__ u16t As0[128 * 32], As1[128 * 32];
    __shared__ u16t Bs0[128 * 32], Bs1[128 * 32];
    facc4 acc[4][4];
    const int z = blockIdx.z;
    gemm_core(xb, args.w[z], As0, As1, Bs0, Bs1, acc);

    const int t    = threadIdx.x;
    const int lane = t & 63;
    const int m16  = lane & 15;
    const int quad = lane >> 4;
    const int wid  = t >> 6;
    const int wm   = (wid & 1) * 64;
    const int wn   = (wid >> 1) * 64;
    const int bm0  = blockIdx.y * 128;
    const int bn0  = blockIdx.x * 128;
    const bool rope = (z < 2);
    u16t* out = args.out[z];
    const float* bias = args.bias[z];

#pragma unroll
    for (int i = 0; i < 4; ++i) {
#pragma unroll
        for (int j = 0; j < 4; ++j) {
            const int n = bn0 + wn + j * 16 + m16;
            const float bn_ = bias[n];
#pragma unroll
            for (int r = 0; r < 4; ++r) {
                const int m = bm0 + wm + i * 16 + quad * 4 + r;
                float v = acc[i][j][r] + bn_;
                // RoPE: pair partner (n^1) lives in lane^1 (same quad, same reg)
                const float part = __shfl_xor(v, 1, 64);
                if (rope) {
                    const int s = m & (S_LEN - 1);
                    const int p = (n & 127) >> 1;
                    const float cs = fcos[s * 64 + p];
                    const float sn = fsin[s * 64 + p];
                    v = (n & 1) ? (part * sn + v * cs) : (v * cs - part * sn);
                }
                out[(size_t)m * E_DIM + n] = f2bf(v);
            }
        }
    }
}

// ---------------- output projection GEMM (fp32 out + bias) ----------------
__global__ __launch_bounds__(256, 2)
void out_gemm(const u16t* __restrict__ sh, const u16t* __restrict__ wob,
              const float* __restrict__ bo, float* __restrict__ out) {
    __shared__ u16t As0[128 * 32], As1[128 * 32];
    __shared__ u16t Bs0[128 * 32], Bs1[128 * 32];
    facc4 acc[4][4];
    gemm_core(sh, wob, As0, As1, Bs0, Bs1, acc);

    const int t    = threadIdx.x;
    const int lane = t & 63;
    const int m16  = lane & 15;
    const int quad = lane >> 4;
    const int wid  = t >> 6;
    const int wm   = (wid & 1) * 64;
    const int wn   = (wid >> 1) * 64;
    const int bm0  = blockIdx.y * 128;
    const int bn0  = blockIdx.x * 128;

#pragma unroll
    for (int i = 0; i < 4; ++i) {
#pragma unroll
        for (int j = 0; j < 4; ++j) {
            const int n = bn0 + wn + j * 16 + m16;
            const float bn_ = bo[n];
#pragma unroll
            for (int r = 0; r < 4; ++r) {
                const int m = bm0 + wm + i * 16 + quad * 4 + r;
                out[(size_t)m * E_DIM + n] = acc[i][j][r] + bn_;
            }
        }
    }
}

// ---------------- per-token head attention, MFMA version ----------------
// One WAVE per token. S = Q.K^T via 4x mfma 16x16x32 (A-frag = Q rows,
// B-frag = K rows, loaded as coalesced 16B chunks from global). Softmax over
// g across 16-lane groups. P transposed through LDS into A-frag (K padded to
// 32 with zeros); PV via 8 MFMAs with V B-frags from an LDS-staged tile.
// Output scattered to shuffled layout sh[b][h*128 + s/16][(s%16)*128 + d].
__global__ __launch_bounds__(256)
void attn_kernel(const u16t* __restrict__ qb, const u16t* __restrict__ kb,
                 const u16t* __restrict__ vb, u16t* __restrict__ sh) {
    __shared__ u16t Vs[4][16 * 136];   // pad 136: 4-way worst on frag reads
    __shared__ u16t Pt[4][16 * 32];    // P in A-frag layout, cols 16..31 = 0

    const int t    = threadIdx.x;
    const int wid  = t >> 6;
    const int lane = t & 63;
    const int m16  = lane & 15;
    const int quad = lane >> 4;
    const int tk   = blockIdx.x * 4 + wid;
    const int b    = tk >> 11;
    const int s    = tk & (S_LEN - 1);
    const size_t row = (size_t)tk * E_DIM;

    // Q,K fragments straight from global (16B per lane per k-step)
    frag8 aq[4], ak[4];
    const u16t* qrow = qb + row + m16 * 128 + quad * 8;
    const u16t* krow = kb + row + m16 * 128 + quad * 8;
#pragma unroll
    for (int ks = 0; ks < 4; ++ks) {
        aq[ks] = *(const frag8*)(qrow + ks * 32);
        ak[ks] = *(const frag8*)(krow + ks * 32);
    }

    // V row -> LDS [16][136]
    u16t* vs = Vs[wid];
#pragma unroll
    for (int c = 0; c < 4; ++c) {
        const int e  = c * 512 + lane * 8;
        const int vr = e >> 7, vc = e & 127;
        *(uint4*)(vs + vr * 136 + vc) = *(const uint4*)(vb + row + e);
    }

    // scores
    facc4 sacc = facc4{0.f, 0.f, 0.f, 0.f};
#pragma unroll
    for (int ks = 0; ks < 4; ++ks)
        sacc = __builtin_amdgcn_mfma_f32_16x16x32_bf16(aq[ks], ak[ks], sacc, 0, 0, 0);

    // softmax over g (16 lanes of the same quad); lane holds rows h=quad*4+r at col g=m16
    float p[4], mx[4], sm[4];
#pragma unroll
    for (int r = 0; r < 4; ++r) { p[r] = sacc[r] * 0.08838834764831845f; mx[r] = p[r]; }
#pragma unroll
    for (int msk = 1; msk < 16; msk <<= 1)
#pragma unroll
        for (int r = 0; r < 4; ++r) mx[r] = fmaxf(mx[r], __shfl_xor(mx[r], msk, 64));
#pragma unroll
    for (int r = 0; r < 4; ++r) { p[r] = __expf(p[r] - mx[r]); sm[r] = p[r]; }
#pragma unroll
    for (int msk = 1; msk < 16; msk <<= 1)
#pragma unroll
        for (int r = 0; r < 4; ++r) sm[r] += __shfl_xor(sm[r], msk, 64);

    // P -> LDS in A-frag layout: Pt[h][g], h rows of 32 (cols 16..31 zero)
    u16t* pt = Pt[wid];
#pragma unroll
    for (int r = 0; r < 4; ++r)
        pt[(quad * 4 + r) * 32 + m16] = f2bf(p[r] / sm[r]);
    *(uint2*)(pt + m16 * 32 + 16 + quad * 4) = uint2{0u, 0u};   // zero pad

    __syncthreads();

    // A-frag of P: lane holds P[m16][quad*8+j]
    const frag8 aP = *(const frag8*)(pt + m16 * 32 + quad * 8);

    // PV: 8 d-blocks of 16; B-frag j: V[(quad*8+j)&15][dblk*16+m16]
    // (quads 2,3 read duplicate addresses of quads 0,1 -> broadcast; their
    //  products are zeroed by the K-padding in aP)
    facc4 oacc[8];
#pragma unroll
    for (int d = 0; d < 8; ++d) oacc[d] = facc4{0.f, 0.f, 0.f, 0.f};
#pragma unroll
    for (int dblk = 0; dblk < 8; ++dblk) {
        union { u16t u[8]; frag8 f; } bb;
#pragma unroll
        for (int j = 0; j < 8; ++j)
            bb.u[j] = vs[((quad * 8 + j) & 15) * 136 + dblk * 16 + m16];
        oacc[dblk] = __builtin_amdgcn_mfma_f32_16x16x32_bf16(aP, bb.f, oacc[dblk], 0, 0, 0);
    }

    // scatter to shuffled layout: lane holds out[h=quad*4+r][d=dblk*16+m16]
    const size_t base = ((size_t)b << 22) + (size_t)(s >> 4) * E_DIM
                      + (size_t)((s & 15) * 128);
#pragma unroll
    for (int dblk = 0; dblk < 8; ++dblk) {
        const int d = dblk * 16 + m16;
#pragma unroll
        for (int r = 0; r < 4; ++r) {
            const int h = quad * 4 + r;
            sh[base + ((size_t)h << 18) + d] = f2bf(oacc[dblk][r]);
        }
    }
}

// ---------------- launch ----------------
extern "C" void kernel_launch(void* const* d_in, const int* in_sizes, int n_in,
                              void* d_out, int out_size, void* d_ws, size_t ws_size,
                              hipStream_t stream) {
    const float* x    = (const float*)d_in[0];
    const float* fcos = (const float*)d_in[1];
    const float* fsin = (const float*)d_in[2];
    const float* wq   = (const float*)d_in[3];
    const float* bq   = (const float*)d_in[4];
    const float* wk   = (const float*)d_in[5];
    const float* bk   = (const float*)d_in[6];
    const float* wv   = (const float*)d_in[7];
    const float* bv   = (const float*)d_in[8];
    const float* wo   = (const float*)d_in[9];
    const float* bo   = (const float*)d_in[10];
    float* out = (float*)d_out;

    char* ws = (char*)d_ws;
    u16t* xb  = (u16t*)(ws);                      // 32 MB, reused as shuffled buf
    u16t* qb  = (u16t*)(ws + 33554432ull);
    u16t* kb  = (u16t*)(ws + 67108864ull);
    u16t* vb  = (u16t*)(ws + 100663296ull);
    u16t* wqb = (u16t*)(ws + 134217728ull);
    u16t* wkb = (u16t*)(ws + 142606336ull);
    u16t* wvb = (u16t*)(ws + 150994944ull);
    u16t* wob = (u16t*)(ws + 159383552ull);       // total 160 MB

    cvt_kernel<<<16384, 256, 0, stream>>>(x, xb, 4194304);
    cvt_kernel<<<4096, 256, 0, stream>>>(wq, wqb, 1048576);
    cvt_kernel<<<4096, 256, 0, stream>>>(wk, wkb, 1048576);
    cvt_kernel<<<4096, 256, 0, stream>>>(wv, wvb, 1048576);
    cvt_kernel<<<4096, 256, 0, stream>>>(wo, wob, 1048576);

    QkvArgs qa;
    qa.w[0] = wqb; qa.w[1] = wkb; qa.w[2] = wvb;
    qa.bias[0] = bq; qa.bias[1] = bk; qa.bias[2] = bv;
    qa.out[0] = qb; qa.out[1] = kb; qa.out[2] = vb;
    qkv_gemm<<<dim3(16, 64, 3), 256, 0, stream>>>(xb, qa, fcos, fsin);

    attn_kernel<<<2048, 256, 0, stream>>>(qb, kb, vb, xb);

    out_gemm<<<dim3(16, 64), 256, 0, stream>>>(xb, wob, bo, out);
}